// Round 1
// baseline (320.105 us; speedup 1.0000x reference)
//
#include <hip/hip_runtime.h>
#include <math.h>

#define B_ 4
#define T_ 64
#define D_ 8
#define V_ 2000
#define LOG2PI_F 1.8378770664093453f

// Cholesky of (A + diag(dadd)), returns |L^{-1} eta|^2 and logdet(A+diag(dadd)).
// Only the lower triangle of A is read. Fully unrolled -> all register-resident.
__device__ __forceinline__ float chol_quad(const float A[D_][D_], const float dadd[D_],
                                           const float eta[D_], float& logdet) {
  float L[D_][D_];
  float rs[D_];
  float p0 = 1.f, p1 = 1.f;
#pragma unroll
  for (int j = 0; j < D_; ++j) {
    float c = A[j][j] + dadd[j];
#pragma unroll
    for (int k = 0; k < D_; ++k) {
      if (k < j) c -= L[j][k] * L[j][k];
    }
    if (j < 4) p0 *= c; else p1 *= c;
    float r = rsqrtf(c);
    rs[j] = r;
#pragma unroll
    for (int i = 0; i < D_; ++i) {
      if (i > j) {
        float s = A[i][j];
#pragma unroll
        for (int k = 0; k < D_; ++k) {
          if (k < j) s -= L[i][k] * L[j][k];
        }
        L[i][j] = s * r;
      }
    }
  }
  logdet = __logf(p0) + __logf(p1);
  float z[D_];
  float q = 0.f;
#pragma unroll
  for (int i = 0; i < D_; ++i) {
    float s = eta[i];
#pragma unroll
    for (int k = 0; k < D_; ++k) {
      if (k < i) s -= L[i][k] * z[k];
    }
    z[i] = s * rs[i];
    q = fmaf(z[i], z[i], q);
  }
  return q;
}

// Blocks 0..3: per-batch information-form scan. Blocks 4..35: decoder table.
extern "C" __global__ void __launch_bounds__(64)
k_scan_table(const int* __restrict__ sent, const float* __restrict__ em_mu,
             const float* __restrict__ em_cho, const float* __restrict__ tr_mu,
             const float* __restrict__ tr_cho, const float* __restrict__ dec_mu,
             const float* __restrict__ dec_cho, float* __restrict__ lam0_ws,
             float* __restrict__ eta0_ws, float* __restrict__ table) {
  const int tid = threadIdx.x;
  if (blockIdx.x >= B_) {
    // decoder table: lam1v, eta1, zeta1 in SoA layout [17][V_]
    const int v = (blockIdx.x - B_) * 64 + tid;
    if (v < V_) {
      float sl = 0.f, q = 0.f;
#pragma unroll
      for (int j = 0; j < D_; ++j) {
        float c = dec_cho[v * D_ + j];
        float m = dec_mu[v * D_ + j];
        float l = 1.f / (c * c);
        float e = m * l;
        sl += __logf(l);
        q = fmaf(e, m, q);
        table[j * V_ + v] = l;
        table[(D_ + j) * V_ + v] = e;
      }
      table[16 * V_ + v] = -0.5f * (8.f * LOG2PI_F - sl + q);
    }
    return;
  }

  __shared__ float sC[16][16], sCi[16][16], sLt[16][16];
  __shared__ float sEt[16], sMu[16];
  __shared__ float sM[8][17], sM2[8][17];
  __shared__ float sLam1[8][8], sEta1[8], sWmu[8], sLamw[8];
  const int b = blockIdx.x;

  // load transition_cho (lower triangular) and transition_mu
  for (int e = tid; e < 256; e += 64) sC[e >> 4][e & 15] = tr_cho[e];
  if (tid < 16) sMu[tid] = tr_mu[tid];
  __syncthreads();

  // Cinv (forward substitution per column); C is lower triangular with positive diag
  if (tid < 16) {
    const int j = tid;
    for (int i = 0; i < 16; ++i) sCi[i][j] = 0.f;
    sCi[j][j] = 1.f / sC[j][j];
    for (int i = j + 1; i < 16; ++i) {
      float s = 0.f;
      for (int k = j; k < i; ++k) s += sC[i][k] * sCi[k][j];
      sCi[i][j] = -s / sC[i][i];
    }
  }
  __syncthreads();

  // lam_t = inv(C^T C) = Cinv * Cinv^T
  for (int e = tid; e < 256; e += 64) {
    int i = e >> 4, j = e & 15;
    float s = 0.f;
    for (int k = 0; k < 16; ++k) s += sCi[i][k] * sCi[j][k];
    sLt[i][j] = s;
  }
  __syncthreads();
  if (tid < 16) {
    float s = 0.f;
    for (int j = 0; j < 16; ++j) s += sLt[tid][j] * sMu[j];
    sEt[tid] = s;
  }
  // init carry: lam1 = I, eta1 = 0  (mu=0, var=I in information form)
  sLam1[tid >> 3][tid & 7] = ((tid >> 3) == (tid & 7)) ? 1.f : 0.f;
  if (tid < 8) sEta1[tid] = 0.f;
  __syncthreads();

  for (int t = 0; t < T_; ++t) {
    const int w = sent[b * T_ + t];
    if (tid < 8) {
      float c = em_cho[w * D_ + tid];
      sLamw[tid] = 1.f / (c * c);
      sWmu[tid] = em_mu[w * D_ + tid];
    }
    // build augmented M = [A | B | eta_head]  (A = Lt[0:8,0:8]+lam1, SPD)
    for (int e = tid; e < 136; e += 64) {
      int i = e / 17, j = e % 17;
      float val;
      if (j < 8) val = sLt[i][j] + sLam1[i][j];
      else if (j < 16) val = sLt[i][j];
      else val = sEt[i] + sEta1[i];
      sM[i][j] = val;
    }
    __syncthreads();
    // Gauss-Jordan on A (ping-pong buffers, race-free)
    float (*src)[17] = sM;
    float (*dst)[17] = sM2;
    for (int k = 0; k < 8; ++k) {
      const float piv = 1.f / src[k][k];
      for (int e = tid; e < 136; e += 64) {
        int i = e / 17, j = e % 17;
        float mkj = src[k][j];
        dst[i][j] = (i == k) ? mkj * piv : fmaf(-src[i][k] * piv, mkj, src[i][j]);
      }
      __syncthreads();
      float (*tmp)[17] = src; src = dst; dst = tmp;
    }
    // lam2 = D - C A^{-1} B + diag(lam_w);   C = Lt[8:,0:8], D = Lt[8:,8:]
    {
      int i = tid >> 3, j = tid & 7;
      float s = sLt[8 + i][8 + j];
#pragma unroll
      for (int k = 0; k < 8; ++k) s -= sLt[8 + i][k] * src[k][8 + j];
      if (i == j) s += sLamw[i];
      sLam1[i][j] = s;
      lam0_ws[(b * T_ + t) * 64 + tid] = s;
    }
    // eta2 = eta_tail - C A^{-1} eta_head + lam_w * wmu
    if (tid < 8) {
      float s = sEt[8 + tid];
#pragma unroll
      for (int k = 0; k < 8; ++k) s -= sLt[8 + tid][k] * src[k][16];
      s = fmaf(sLamw[tid], sWmu[tid], s);
      sEta1[tid] = s;
      eta0_ws[(b * T_ + t) * 8 + tid] = s;
    }
    __syncthreads();
  }
}

// One block per (b,t); each thread handles ~8 vocab entries, all in registers.
extern "C" __global__ void __launch_bounds__(256)
k_phase_b(const float* __restrict__ lam0_ws, const float* __restrict__ eta0_ws,
          const float* __restrict__ table, float* __restrict__ out) {
  const int bt = blockIdx.x;
  __shared__ float sL[64];
  __shared__ float sE[8];
  if (threadIdx.x < 64) sL[threadIdx.x] = lam0_ws[bt * 64 + threadIdx.x];
  if (threadIdx.x < 8) sE[threadIdx.x] = eta0_ws[bt * 8 + threadIdx.x];
  __syncthreads();
  float A0[D_][D_], e0[D_];
#pragma unroll
  for (int i = 0; i < D_; ++i) {
    e0[i] = sE[i];
#pragma unroll
    for (int j = 0; j < D_; ++j) A0[i][j] = sL[i * 8 + j];
  }
  float zero[D_];
#pragma unroll
  for (int j = 0; j < D_; ++j) zero[j] = 0.f;
  float ld0;
  float q0 = chol_quad(A0, zero, e0, ld0);
  const float zeta0 = -0.5f * (8.f * LOG2PI_F - ld0 + q0);

#pragma unroll 1
  for (int it = 0; it < 8; ++it) {
    int v = threadIdx.x + it * 256;
    if (v < V_) {
      float dl[D_], ef[D_];
#pragma unroll
      for (int j = 0; j < D_; ++j) {
        dl[j] = table[j * V_ + v];
        ef[j] = e0[j] + table[(D_ + j) * V_ + v];
      }
      float z1 = table[16 * V_ + v];
      float ldn;
      float qn = chol_quad(A0, dl, ef, ldn);
      float zeta_n = -0.5f * (8.f * LOG2PI_F - ldn + qn);
      out[bt * V_ + v] = zeta0 + z1 - zeta_n;
    }
  }
}

extern "C" void kernel_launch(void* const* d_in, const int* in_sizes, int n_in,
                              void* d_out, int out_size, void* d_ws, size_t ws_size,
                              hipStream_t stream) {
  const int* sent = (const int*)d_in[0];
  // d_in[1] = masks (unused by the reference computation)
  const float* em_mu = (const float*)d_in[2];
  const float* em_cho = (const float*)d_in[3];
  const float* tr_mu = (const float*)d_in[4];
  const float* tr_cho = (const float*)d_in[5];
  const float* dec_mu = (const float*)d_in[6];
  const float* dec_cho = (const float*)d_in[7];
  float* out = (float*)d_out;

  float* ws = (float*)d_ws;
  float* lam0_ws = ws;                        // 256*64 floats
  float* eta0_ws = ws + 256 * 64;             // 256*8 floats
  float* table = ws + 256 * 64 + 256 * 8;     // 17*2000 floats

  dim3 g1(B_ + (V_ + 63) / 64);
  k_scan_table<<<g1, dim3(64), 0, stream>>>(sent, em_mu, em_cho, tr_mu, tr_cho,
                                            dec_mu, dec_cho, lam0_ws, eta0_ws, table);
  k_phase_b<<<dim3(256), dim3(256), 0, stream>>>(lam0_ws, eta0_ws, table, out);
}

// Round 2
// 77.758 us; speedup vs baseline: 4.1167x; 4.1167x over previous
//
#include <hip/hip_runtime.h>
#include <math.h>

#define B_ 4
#define T_ 64
#define D_ 8
#define V_ 2000
#define LOG2PI_F 1.8378770664093453f

#define RCP(x) __builtin_amdgcn_rcpf(x)

// Cholesky of (A + diag(dadd)), returns |L^{-1} eta|^2 and logdet(A+diag(dadd)).
__device__ __forceinline__ float chol_quad(const float A[D_][D_], const float dadd[D_],
                                           const float eta[D_], float& logdet) {
  float L[D_][D_];
  float rs[D_];
  float p0 = 1.f, p1 = 1.f;
#pragma unroll
  for (int j = 0; j < D_; ++j) {
    float c = A[j][j] + dadd[j];
#pragma unroll
    for (int k = 0; k < D_; ++k) {
      if (k < j) c -= L[j][k] * L[j][k];
    }
    if (j < 4) p0 *= c; else p1 *= c;
    float r = rsqrtf(c);
    rs[j] = r;
#pragma unroll
    for (int i = 0; i < D_; ++i) {
      if (i > j) {
        float s = A[i][j];
#pragma unroll
        for (int k = 0; k < D_; ++k) {
          if (k < j) s -= L[i][k] * L[j][k];
        }
        L[i][j] = s * r;
      }
    }
  }
  logdet = __logf(p0) + __logf(p1);
  float z[D_];
  float q = 0.f;
#pragma unroll
  for (int i = 0; i < D_; ++i) {
    float s = eta[i];
#pragma unroll
    for (int k = 0; k < D_; ++k) {
      if (k < i) s -= L[i][k] * z[k];
    }
    z[i] = s * rs[i];
    q = fmaf(z[i], z[i], q);
  }
  return q;
}

// Blocks 0..3: per-batch scan, ONE WAVE, register-resident, shuffle-based GJ.
// Blocks 4..35: decoder table (lam1v, eta1, zeta1) in SoA layout.
extern "C" __global__ void __launch_bounds__(64)
k_scan_table(const int* __restrict__ sent, const float* __restrict__ em_mu,
             const float* __restrict__ em_cho, const float* __restrict__ tr_mu,
             const float* __restrict__ tr_cho, const float* __restrict__ dec_mu,
             const float* __restrict__ dec_cho, float* __restrict__ lam0_ws,
             float* __restrict__ eta0_ws, float* __restrict__ table) {
  const int tid = threadIdx.x;
  if (blockIdx.x >= B_) {
    const int v = (blockIdx.x - B_) * 64 + tid;
    if (v < V_) {
      float sl = 0.f, q = 0.f;
#pragma unroll
      for (int j = 0; j < D_; ++j) {
        float c = dec_cho[v * D_ + j];
        float m = dec_mu[v * D_ + j];
        float l = 1.f / (c * c);
        float e = m * l;
        sl += __logf(l);
        q = fmaf(e, m, q);
        table[j * V_ + v] = l;
        table[(D_ + j) * V_ + v] = e;
      }
      table[16 * V_ + v] = -0.5f * (8.f * LOG2PI_F - sl + q);
    }
    return;
  }

  __shared__ float sC[16][16], sCi[16][16], sLt[16][16];
  __shared__ float sEt[16], sMu[16];
  const int b = blockIdx.x;

  // ---- preamble: lam_t = inv(C^T C) via Cinv columns in registers ----
  for (int e = tid; e < 256; e += 64) sC[e >> 4][e & 15] = tr_cho[e];
  if (tid < 16) sMu[tid] = tr_mu[tid];
  __syncthreads();
  if (tid < 16) {
    const int j = tid;
    float col[16];
#pragma unroll
    for (int i = 0; i < 16; ++i) {
      float s = (i == j) ? 1.f : 0.f;
#pragma unroll
      for (int k = 0; k < 16; ++k) {
        if (k < i) s = fmaf(-sC[i][k], col[k], s);
      }
      col[i] = s * RCP(sC[i][i]);
    }
#pragma unroll
    for (int i = 0; i < 16; ++i) sCi[i][j] = col[i];
  }
  __syncthreads();
  for (int e = tid; e < 256; e += 64) {
    int i = e >> 4, jq = e & 15;
    float s = 0.f;
#pragma unroll
    for (int k = 0; k < 16; ++k) s = fmaf(sCi[i][k], sCi[jq][k], s);
    sLt[i][jq] = s;
  }
  __syncthreads();
  if (tid < 16) {
    float s = 0.f;
#pragma unroll
    for (int k = 0; k < 16; ++k) s = fmaf(sLt[tid][k], sMu[k], s);
    sEt[tid] = s;
  }
  __syncthreads();

  // ---- register layout: lane = (ii,jj) of 8x8 ----
  const int ii = tid >> 3, jj = tid & 7;
  const float ltAA = sLt[ii][jj];
  const float ltAB = sLt[ii][8 + jj];
  const float ltBA = sLt[8 + ii][jj];
  const float ltBB = sLt[8 + ii][8 + jj];
  const float etH = sEt[ii];
  const float etT = sEt[8 + ii];
  float lam1 = (ii == jj) ? 1.f : 0.f;
  float eta1 = 0.f;

  const int sw = sent[b * T_ + tid];  // all 64 word ids in registers

  // prefetch t=0 word data
  int wid = __shfl(sw, 0);
  float ec = em_cho[wid * D_ + ii];
  float em = em_mu[wid * D_ + ii];

#pragma unroll 1
  for (int t = 0; t < T_; ++t) {
    const float lamw = RCP(ec * ec);
    const float wmu = em;
    if (t < T_ - 1) {  // prefetch next step's word data (hides under GJ)
      int wn = __shfl(sw, t + 1);
      ec = em_cho[wn * D_ + ii];
      em = em_mu[wn * D_ + ii];
    }

    float A = ltAA + lam1;   // SPD 8x8
    float Bm = ltAB;         // rhs block
    float ev = etH + eta1;   // rhs vector (row-replicated)

    // Gauss-Jordan: A -> I, Bm -> A^{-1}B, ev -> A^{-1}e. No LDS, no barriers.
#pragma unroll
    for (int k = 0; k < 8; ++k) {
      float piv = __shfl(A, k * 9);
      float rp = RCP(piv);
      float rowA = __shfl(A, (k << 3) | jj);
      float colA = __shfl(A, (ii << 3) | k);
      float rowB = __shfl(Bm, (k << 3) | jj);
      float rowE = __shfl(ev, (k << 3) | jj);
      float f = colA * rp;
      bool pr = (ii == k);
      A = pr ? rowA * rp : fmaf(-f, rowA, A);
      Bm = pr ? rowB * rp : fmaf(-f, rowB, Bm);
      ev = pr ? rowE * rp : fmaf(-f, rowE, ev);
    }

    // Schur: lam2 = Dm - C A^{-1} B + diag(lamw); eta2 = e_t - C A^{-1} e_h + lamw*wmu
    float s = ltBB;
    float se = etT;
#pragma unroll
    for (int k = 0; k < 8; ++k) {
      float c_ik = __shfl(ltBA, (ii << 3) | k);
      float b_kj = __shfl(Bm, (k << 3) | jj);
      float e_k = __shfl(ev, (k << 3) | jj);
      s = fmaf(-c_ik, b_kj, s);
      se = fmaf(-c_ik, e_k, se);
    }
    const float lam2 = (ii == jj) ? s + lamw : s;
    const float eta2 = fmaf(lamw, wmu, se);

    lam0_ws[(b * T_ + t) * 64 + tid] = lam2;
    if (jj == 0) eta0_ws[(b * T_ + t) * 8 + ii] = eta2;
    lam1 = lam2;
    eta1 = eta2;
  }
}

// One block per (b,t); each thread handles ~8 vocab entries, all in registers.
extern "C" __global__ void __launch_bounds__(256)
k_phase_b(const float* __restrict__ lam0_ws, const float* __restrict__ eta0_ws,
          const float* __restrict__ table, float* __restrict__ out) {
  const int bt = blockIdx.x;
  __shared__ float sL[64];
  __shared__ float sE[8];
  if (threadIdx.x < 64) sL[threadIdx.x] = lam0_ws[bt * 64 + threadIdx.x];
  if (threadIdx.x < 8) sE[threadIdx.x] = eta0_ws[bt * 8 + threadIdx.x];
  __syncthreads();
  float A0[D_][D_], e0[D_];
#pragma unroll
  for (int i = 0; i < D_; ++i) {
    e0[i] = sE[i];
#pragma unroll
    for (int j = 0; j < D_; ++j) A0[i][j] = sL[i * 8 + j];
  }
  float zero[D_];
#pragma unroll
  for (int j = 0; j < D_; ++j) zero[j] = 0.f;
  float ld0;
  float q0 = chol_quad(A0, zero, e0, ld0);
  const float zeta0 = -0.5f * (8.f * LOG2PI_F - ld0 + q0);

#pragma unroll 1
  for (int it = 0; it < 8; ++it) {
    int v = threadIdx.x + it * 256;
    if (v < V_) {
      float dl[D_], ef[D_];
#pragma unroll
      for (int j = 0; j < D_; ++j) {
        dl[j] = table[j * V_ + v];
        ef[j] = e0[j] + table[(D_ + j) * V_ + v];
      }
      float z1 = table[16 * V_ + v];
      float ldn;
      float qn = chol_quad(A0, dl, ef, ldn);
      float zeta_n = -0.5f * (8.f * LOG2PI_F - ldn + qn);
      out[bt * V_ + v] = zeta0 + z1 - zeta_n;
    }
  }
}

extern "C" void kernel_launch(void* const* d_in, const int* in_sizes, int n_in,
                              void* d_out, int out_size, void* d_ws, size_t ws_size,
                              hipStream_t stream) {
  const int* sent = (const int*)d_in[0];
  const float* em_mu = (const float*)d_in[2];
  const float* em_cho = (const float*)d_in[3];
  const float* tr_mu = (const float*)d_in[4];
  const float* tr_cho = (const float*)d_in[5];
  const float* dec_mu = (const float*)d_in[6];
  const float* dec_cho = (const float*)d_in[7];
  float* out = (float*)d_out;

  float* ws = (float*)d_ws;
  float* lam0_ws = ws;                     // 256*64 floats
  float* eta0_ws = ws + 256 * 64;          // 256*8 floats
  float* table = ws + 256 * 64 + 256 * 8;  // 17*2000 floats

  dim3 g1(B_ + (V_ + 63) / 64);
  k_scan_table<<<g1, dim3(64), 0, stream>>>(sent, em_mu, em_cho, tr_mu, tr_cho,
                                            dec_mu, dec_cho, lam0_ws, eta0_ws, table);
  k_phase_b<<<dim3(256), dim3(256), 0, stream>>>(lam0_ws, eta0_ws, table, out);
}

// Round 3
// 76.474 us; speedup vs baseline: 4.1858x; 1.0168x over previous
//
#include <hip/hip_runtime.h>
#include <math.h>

#define B_ 4
#define T_ 64
#define D_ 8
#define V_ 2000
#define LOG2PI_F 1.8378770664093453f

#define RCP(x) __builtin_amdgcn_rcpf(x)

__device__ __forceinline__ float rdl(float v, int lane) {
  return __int_as_float(__builtin_amdgcn_readlane(__float_as_int(v), lane));
}

// Cholesky of (A + diag(dadd)), returns |L^{-1} eta|^2 and logdet(A+diag(dadd)).
__device__ __forceinline__ float chol_quad(const float A[D_][D_], const float dadd[D_],
                                           const float eta[D_], float& logdet) {
  float L[D_][D_];
  float rs[D_];
  float p0 = 1.f, p1 = 1.f;
#pragma unroll
  for (int j = 0; j < D_; ++j) {
    float c = A[j][j] + dadd[j];
#pragma unroll
    for (int k = 0; k < D_; ++k) {
      if (k < j) c -= L[j][k] * L[j][k];
    }
    if (j < 4) p0 *= c; else p1 *= c;
    float r = rsqrtf(c);
    rs[j] = r;
#pragma unroll
    for (int i = 0; i < D_; ++i) {
      if (i > j) {
        float s = A[i][j];
#pragma unroll
        for (int k = 0; k < D_; ++k) {
          if (k < j) s -= L[i][k] * L[j][k];
        }
        L[i][j] = s * r;
      }
    }
  }
  logdet = __logf(p0) + __logf(p1);
  float z[D_];
  float q = 0.f;
#pragma unroll
  for (int i = 0; i < D_; ++i) {
    float s = eta[i];
#pragma unroll
    for (int k = 0; k < D_; ++k) {
      if (k < i) s -= L[i][k] * z[k];
    }
    z[i] = s * rs[i];
    q = fmaf(z[i], z[i], q);
  }
  return q;
}

// Blocks 0..3: per-batch scan, one wave, row-per-lane, readlane-based bordered
// Gaussian elimination (no LDS / no DS ops in the hot loop).
// Blocks 4..35: decoder table (lam1v, eta1, zeta1) in SoA layout.
extern "C" __global__ void __launch_bounds__(64)
k_scan_table(const int* __restrict__ sent, const float* __restrict__ em_mu,
             const float* __restrict__ em_cho, const float* __restrict__ tr_mu,
             const float* __restrict__ tr_cho, const float* __restrict__ dec_mu,
             const float* __restrict__ dec_cho, float* __restrict__ lam0_ws,
             float* __restrict__ eta0_ws, float* __restrict__ table) {
  const int tid = threadIdx.x;
  if (blockIdx.x >= B_) {
    const int v = (blockIdx.x - B_) * 64 + tid;
    if (v < V_) {
      float sl = 0.f, q = 0.f;
#pragma unroll
      for (int j = 0; j < D_; ++j) {
        float c = dec_cho[v * D_ + j];
        float m = dec_mu[v * D_ + j];
        float l = 1.f / (c * c);
        float e = m * l;
        sl += __logf(l);
        q = fmaf(e, m, q);
        table[j * V_ + v] = l;
        table[(D_ + j) * V_ + v] = e;
      }
      table[16 * V_ + v] = -0.5f * (8.f * LOG2PI_F - sl + q);
    }
    return;
  }

  __shared__ float sC[16][16], sCi[16][16], sLt[16][16];
  __shared__ float sEt[16], sMu[16];
  const int b = blockIdx.x;

  // ---- preamble: lam_t = inv(C^T C), eta_t = lam_t @ mu ----
  for (int e = tid; e < 256; e += 64) sC[e >> 4][e & 15] = tr_cho[e];
  if (tid < 16) sMu[tid] = tr_mu[tid];
  __syncthreads();
  if (tid < 16) {
    const int j = tid;
    float col[16];
#pragma unroll
    for (int i = 0; i < 16; ++i) {
      float s = (i == j) ? 1.f : 0.f;
#pragma unroll
      for (int k = 0; k < 16; ++k) {
        if (k < i) s = fmaf(-sC[i][k], col[k], s);
      }
      col[i] = s * RCP(sC[i][i]);
    }
#pragma unroll
    for (int i = 0; i < 16; ++i) sCi[i][j] = col[i];
  }
  __syncthreads();
  for (int e = tid; e < 256; e += 64) {
    int i = e >> 4, jq = e & 15;
    float s = 0.f;
#pragma unroll
    for (int k = 0; k < 16; ++k) s = fmaf(sCi[i][k], sCi[jq][k], s);
    sLt[i][jq] = s;
  }
  __syncthreads();
  if (tid < 16) {
    float s = 0.f;
#pragma unroll
    for (int k = 0; k < 16; ++k) s = fmaf(sLt[tid][k], sMu[k], s);
    sEt[tid] = s;
  }
  __syncthreads();

  // ---- row-per-lane register state: lane i holds row i ----
  const int i = tid & 7;
  float ltAA[8], ltAB[8], ltBA[8], ltBB[8];
#pragma unroll
  for (int j = 0; j < 8; ++j) {
    ltAA[j] = sLt[i][j];
    ltAB[j] = sLt[i][8 + j];
    ltBA[j] = sLt[8 + i][j];
    ltBB[j] = sLt[8 + i][8 + j];
  }
  const float etH = sEt[i], etT = sEt[8 + i];

  float lam[8];
#pragma unroll
  for (int j = 0; j < 8; ++j) lam[j] = (j == i) ? 1.f : 0.f;
  float eta = 0.f;

  const int sw = sent[b * T_ + tid];  // lane t holds word id of step t
  int w0 = __builtin_amdgcn_readlane(sw, 0);
  float ec = em_cho[w0 * D_ + i];
  float em = em_mu[w0 * D_ + i];

  float* lamOut = lam0_ws + b * T_ * 64;
  float* etaOut = eta0_ws + b * T_ * 8;

#pragma unroll 1
  for (int t = 0; t < T_; ++t) {
    const float lamw = RCP(ec * ec);
    const float wmu = em;
    if (t + 1 < T_) {  // prefetch next word's data (hides under elimination)
      int wn = __builtin_amdgcn_readlane(sw, t + 1);
      ec = em_cho[wn * D_ + i];
      em = em_mu[wn * D_ + i];
    }

    float A[8], Bm[8], Cr[8], Dm[8];
#pragma unroll
    for (int j = 0; j < 8; ++j) A[j] = ltAA[j] + lam[j];
    float ev = etH + eta;
    float et = etT;

    // ---- iter 0 (B/C/D sourced from lt registers, no copy) ----
    {
      float srA[8], srB[8];
#pragma unroll
      for (int j = 0; j < 8; ++j) srA[j] = rdl(A[j], 0);
#pragma unroll
      for (int j = 0; j < 8; ++j) srB[j] = rdl(ltAB[j], 0);
      float srE = rdl(ev, 0);
      float rp = RCP(srA[0]);
      float f1 = (i == 0) ? 0.f : A[0] * rp;
      float f2 = ltBA[0] * rp;
#pragma unroll
      for (int j = 1; j < 8; ++j) {
        A[j] = fmaf(-f1, srA[j], A[j]);
        Cr[j] = fmaf(-f2, srA[j], ltBA[j]);
      }
#pragma unroll
      for (int j = 0; j < 8; ++j) {
        Bm[j] = fmaf(-f1, srB[j], ltAB[j]);
        Dm[j] = fmaf(-f2, srB[j], ltBB[j]);
      }
      ev = fmaf(-f1, srE, ev);
      et = fmaf(-f2, srE, et);
    }
    // ---- iters 1..7 ----
#pragma unroll
    for (int k = 1; k < 8; ++k) {
      float srA[8], srB[8];
#pragma unroll
      for (int j = 0; j < 8; ++j) {
        if (j >= k) srA[j] = rdl(A[j], k);
      }
#pragma unroll
      for (int j = 0; j < 8; ++j) srB[j] = rdl(Bm[j], k);
      float srE = rdl(ev, k);
      float rp = RCP(srA[k]);
      float f1 = (i == k) ? 0.f : A[k] * rp;
      float f2 = Cr[k] * rp;
#pragma unroll
      for (int j = k + 1; j < 8; ++j) {
        A[j] = fmaf(-f1, srA[j], A[j]);
        Cr[j] = fmaf(-f2, srA[j], Cr[j]);
      }
#pragma unroll
      for (int j = 0; j < 8; ++j) {
        Bm[j] = fmaf(-f1, srB[j], Bm[j]);
        Dm[j] = fmaf(-f2, srB[j], Dm[j]);
      }
      ev = fmaf(-f1, srE, ev);
      et = fmaf(-f2, srE, et);
    }

    // epilogue: lam2 = Dm + diag(lamw); eta2 = et + lamw*wmu
#pragma unroll
    for (int j = 0; j < 8; ++j) lam[j] = (j == i) ? Dm[j] + lamw : Dm[j];
    eta = fmaf(lamw, wmu, et);

    if (tid < 8) {
      float4* dst = (float4*)(lamOut + t * 64 + i * 8);
      dst[0] = make_float4(lam[0], lam[1], lam[2], lam[3]);
      dst[1] = make_float4(lam[4], lam[5], lam[6], lam[7]);
      etaOut[t * 8 + i] = eta;
    }
  }
}

// 512 blocks: (b,t) = blockIdx>>1, half = blockIdx&1; 4 cells per thread.
extern "C" __global__ void __launch_bounds__(256)
k_phase_b(const float* __restrict__ lam0_ws, const float* __restrict__ eta0_ws,
          const float* __restrict__ table, float* __restrict__ out) {
  const int bt = blockIdx.x >> 1;
  const int half = blockIdx.x & 1;
  __shared__ float sL[64];
  __shared__ float sE[8];
  if (threadIdx.x < 64) sL[threadIdx.x] = lam0_ws[bt * 64 + threadIdx.x];
  if (threadIdx.x < 8) sE[threadIdx.x] = eta0_ws[bt * 8 + threadIdx.x];
  __syncthreads();
  float A0[D_][D_], e0[D_];
#pragma unroll
  for (int ii = 0; ii < D_; ++ii) {
    e0[ii] = sE[ii];
#pragma unroll
    for (int j = 0; j < D_; ++j) A0[ii][j] = sL[ii * 8 + j];
  }
  float zero[D_];
#pragma unroll
  for (int j = 0; j < D_; ++j) zero[j] = 0.f;
  float ld0;
  float q0 = chol_quad(A0, zero, e0, ld0);
  const float zeta0 = -0.5f * (8.f * LOG2PI_F - ld0 + q0);

#pragma unroll 1
  for (int it = 0; it < 4; ++it) {
    int off = it * 256 + threadIdx.x;
    if (off < 1000) {
      int v = half * 1000 + off;
      float dl[D_], ef[D_];
#pragma unroll
      for (int j = 0; j < D_; ++j) {
        dl[j] = table[j * V_ + v];
        ef[j] = e0[j] + table[(D_ + j) * V_ + v];
      }
      float z1 = table[16 * V_ + v];
      float ldn;
      float qn = chol_quad(A0, dl, ef, ldn);
      float zeta_n = -0.5f * (8.f * LOG2PI_F - ldn + qn);
      out[bt * V_ + v] = zeta0 + z1 - zeta_n;
    }
  }
}

extern "C" void kernel_launch(void* const* d_in, const int* in_sizes, int n_in,
                              void* d_out, int out_size, void* d_ws, size_t ws_size,
                              hipStream_t stream) {
  const int* sent = (const int*)d_in[0];
  const float* em_mu = (const float*)d_in[2];
  const float* em_cho = (const float*)d_in[3];
  const float* tr_mu = (const float*)d_in[4];
  const float* tr_cho = (const float*)d_in[5];
  const float* dec_mu = (const float*)d_in[6];
  const float* dec_cho = (const float*)d_in[7];
  float* out = (float*)d_out;

  float* ws = (float*)d_ws;
  float* lam0_ws = ws;                     // 256*64 floats
  float* eta0_ws = ws + 256 * 64;          // 256*8 floats
  float* table = ws + 256 * 64 + 256 * 8;  // 17*2000 floats

  dim3 g1(B_ + (V_ + 63) / 64);
  k_scan_table<<<g1, dim3(64), 0, stream>>>(sent, em_mu, em_cho, tr_mu, tr_cho,
                                            dec_mu, dec_cho, lam0_ws, eta0_ws, table);
  k_phase_b<<<dim3(512), dim3(256), 0, stream>>>(lam0_ws, eta0_ws, table, out);
}

// Round 4
// 58.845 us; speedup vs baseline: 5.4398x; 1.2996x over previous
//
#include <hip/hip_runtime.h>
#include <math.h>

#define B_ 4
#define T_ 64
#define D_ 8
#define V_ 2000
#define LOG2PI_F 1.8378770664093453f

#define RCP(x) __builtin_amdgcn_rcpf(x)

__device__ __forceinline__ float rdl(float v, int lane) {
  return __int_as_float(__builtin_amdgcn_readlane(__float_as_int(v), lane));
}

// Cholesky of (A + diag(dadd)), returns |L^{-1} eta|^2 and logdet(A+diag(dadd)).
__device__ __forceinline__ float chol_quad(const float A[D_][D_], const float dadd[D_],
                                           const float eta[D_], float& logdet) {
  float L[D_][D_];
  float rs[D_];
  float p0 = 1.f, p1 = 1.f;
#pragma unroll
  for (int j = 0; j < D_; ++j) {
    float c = A[j][j] + dadd[j];
#pragma unroll
    for (int k = 0; k < D_; ++k) {
      if (k < j) c -= L[j][k] * L[j][k];
    }
    if (j < 4) p0 *= c; else p1 *= c;
    float r = rsqrtf(c);
    rs[j] = r;
#pragma unroll
    for (int i = 0; i < D_; ++i) {
      if (i > j) {
        float s = A[i][j];
#pragma unroll
        for (int k = 0; k < D_; ++k) {
          if (k < j) s -= L[i][k] * L[j][k];
        }
        L[i][j] = s * r;
      }
    }
  }
  logdet = __logf(p0) + __logf(p1);
  float z[D_];
  float q = 0.f;
#pragma unroll
  for (int i = 0; i < D_; ++i) {
    float s = eta[i];
#pragma unroll
    for (int k = 0; k < D_; ++k) {
      if (k < i) s -= L[i][k] * z[k];
    }
    z[i] = s * rs[i];
    q = fmaf(z[i], z[i], q);
  }
  return q;
}

// Blocks 0..3: per-batch scan. All word data staged to LDS up front (bulk HBM
// fetch, 128 txns in flight); hot loop has no global loads. Row-per-lane,
// readlane-based bordered Gaussian elimination.
// Blocks 4..35: decoder table (lam1v, eta1, zeta1) in SoA layout.
extern "C" __global__ void __launch_bounds__(64)
k_scan_table(const int* __restrict__ sent, const float* __restrict__ em_mu,
             const float* __restrict__ em_cho, const float* __restrict__ tr_mu,
             const float* __restrict__ tr_cho, const float* __restrict__ dec_mu,
             const float* __restrict__ dec_cho, float* __restrict__ lam0_ws,
             float* __restrict__ eta0_ws, float* __restrict__ table) {
  const int tid = threadIdx.x;
  if (blockIdx.x >= B_) {
    const int v = (blockIdx.x - B_) * 64 + tid;
    if (v < V_) {
      float sl = 0.f, q = 0.f;
#pragma unroll
      for (int j = 0; j < D_; ++j) {
        float c = dec_cho[v * D_ + j];
        float m = dec_mu[v * D_ + j];
        float l = 1.f / (c * c);
        float e = m * l;
        sl += __logf(l);
        q = fmaf(e, m, q);
        table[j * V_ + v] = l;
        table[(D_ + j) * V_ + v] = e;
      }
      table[16 * V_ + v] = -0.5f * (8.f * LOG2PI_F - sl + q);
    }
    return;
  }

  __shared__ float sC[16][16], sCi[16][16], sLt[16][16];
  __shared__ float sEt[16], sMu[16];
  __shared__ float sLamW[T_][8], sWmuT[T_][8];
  const int b = blockIdx.x;

  // ---- stage ALL word data: lane t loads word w_t's 8 cho + 8 mu ----
  const int sw = sent[b * T_ + tid];  // lane t holds word id of step t
  {
    const float4* pc = (const float4*)(em_cho + sw * D_);
    const float4* pm = (const float4*)(em_mu + sw * D_);
    float4 c0 = pc[0], c1 = pc[1];
    float4 m0 = pm[0], m1 = pm[1];
    sLamW[tid][0] = RCP(c0.x * c0.x);
    sLamW[tid][1] = RCP(c0.y * c0.y);
    sLamW[tid][2] = RCP(c0.z * c0.z);
    sLamW[tid][3] = RCP(c0.w * c0.w);
    sLamW[tid][4] = RCP(c1.x * c1.x);
    sLamW[tid][5] = RCP(c1.y * c1.y);
    sLamW[tid][6] = RCP(c1.z * c1.z);
    sLamW[tid][7] = RCP(c1.w * c1.w);
    sWmuT[tid][0] = m0.x; sWmuT[tid][1] = m0.y;
    sWmuT[tid][2] = m0.z; sWmuT[tid][3] = m0.w;
    sWmuT[tid][4] = m1.x; sWmuT[tid][5] = m1.y;
    sWmuT[tid][6] = m1.z; sWmuT[tid][7] = m1.w;
  }

  // ---- preamble: lam_t = inv(C^T C), eta_t = lam_t @ mu ----
  for (int e = tid; e < 256; e += 64) sC[e >> 4][e & 15] = tr_cho[e];
  if (tid < 16) sMu[tid] = tr_mu[tid];
  __syncthreads();
  if (tid < 16) {
    const int j = tid;
    float col[16];
#pragma unroll
    for (int i = 0; i < 16; ++i) {
      float s = (i == j) ? 1.f : 0.f;
#pragma unroll
      for (int k = 0; k < 16; ++k) {
        if (k < i) s = fmaf(-sC[i][k], col[k], s);
      }
      col[i] = s * RCP(sC[i][i]);
    }
#pragma unroll
    for (int i = 0; i < 16; ++i) sCi[i][j] = col[i];
  }
  __syncthreads();
  for (int e = tid; e < 256; e += 64) {
    int i = e >> 4, jq = e & 15;
    float s = 0.f;
#pragma unroll
    for (int k = 0; k < 16; ++k) s = fmaf(sCi[i][k], sCi[jq][k], s);
    sLt[i][jq] = s;
  }
  __syncthreads();
  if (tid < 16) {
    float s = 0.f;
#pragma unroll
    for (int k = 0; k < 16; ++k) s = fmaf(sLt[tid][k], sMu[k], s);
    sEt[tid] = s;
  }
  __syncthreads();

  // ---- row-per-lane register state: lane i holds row i ----
  const int i = tid & 7;
  float ltAA[8], ltAB[8], ltBA[8], ltBB[8];
#pragma unroll
  for (int j = 0; j < 8; ++j) {
    ltAA[j] = sLt[i][j];
    ltAB[j] = sLt[i][8 + j];
    ltBA[j] = sLt[8 + i][j];
    ltBB[j] = sLt[8 + i][8 + j];
  }
  const float etH = sEt[i], etT = sEt[8 + i];

  float lam[8];
#pragma unroll
  for (int j = 0; j < 8; ++j) lam[j] = (j == i) ? 1.f : 0.f;
  float eta = 0.f;

  float* lamOut = lam0_ws + b * T_ * 64;
  float* etaOut = eta0_ws + b * T_ * 8;

  float lamw = sLamW[0][i];
  float wmu = sWmuT[0][i];

#pragma unroll 1
  for (int t = 0; t < T_; ++t) {
    // prefetch next step's word data from LDS (latency hides under elimination)
    float lamw_n = sLamW[(t + 1) & (T_ - 1)][i];
    float wmu_n = sWmuT[(t + 1) & (T_ - 1)][i];

    float A[8], Bm[8], Cr[8], Dm[8];
#pragma unroll
    for (int j = 0; j < 8; ++j) A[j] = ltAA[j] + lam[j];
    float ev = etH + eta;
    float et = etT;

    // ---- iter 0 (B/C/D sourced from lt registers, no copy) ----
    {
      float srA[8], srB[8];
#pragma unroll
      for (int j = 0; j < 8; ++j) srA[j] = rdl(A[j], 0);
#pragma unroll
      for (int j = 0; j < 8; ++j) srB[j] = rdl(ltAB[j], 0);
      float srE = rdl(ev, 0);
      float rp = RCP(srA[0]);
      float f1 = (i == 0) ? 0.f : A[0] * rp;
      float f2 = ltBA[0] * rp;
#pragma unroll
      for (int j = 1; j < 8; ++j) {
        A[j] = fmaf(-f1, srA[j], A[j]);
        Cr[j] = fmaf(-f2, srA[j], ltBA[j]);
      }
#pragma unroll
      for (int j = 0; j < 8; ++j) {
        Bm[j] = fmaf(-f1, srB[j], ltAB[j]);
        Dm[j] = fmaf(-f2, srB[j], ltBB[j]);
      }
      ev = fmaf(-f1, srE, ev);
      et = fmaf(-f2, srE, et);
    }
    // ---- iters 1..7 ----
#pragma unroll
    for (int k = 1; k < 8; ++k) {
      float srA[8], srB[8];
#pragma unroll
      for (int j = 0; j < 8; ++j) {
        if (j >= k) srA[j] = rdl(A[j], k);
      }
#pragma unroll
      for (int j = 0; j < 8; ++j) srB[j] = rdl(Bm[j], k);
      float srE = rdl(ev, k);
      float rp = RCP(srA[k]);
      float f1 = (i == k) ? 0.f : A[k] * rp;
      float f2 = Cr[k] * rp;
#pragma unroll
      for (int j = k + 1; j < 8; ++j) {
        A[j] = fmaf(-f1, srA[j], A[j]);
        Cr[j] = fmaf(-f2, srA[j], Cr[j]);
      }
#pragma unroll
      for (int j = 0; j < 8; ++j) {
        Bm[j] = fmaf(-f1, srB[j], Bm[j]);
        Dm[j] = fmaf(-f2, srB[j], Dm[j]);
      }
      ev = fmaf(-f1, srE, ev);
      et = fmaf(-f2, srE, et);
    }

    // epilogue: lam2 = Dm + diag(lamw); eta2 = et + lamw*wmu
#pragma unroll
    for (int j = 0; j < 8; ++j) lam[j] = (j == i) ? Dm[j] + lamw : Dm[j];
    eta = fmaf(lamw, wmu, et);

    if (tid < 8) {
      float4* dst = (float4*)(lamOut + t * 64 + i * 8);
      dst[0] = make_float4(lam[0], lam[1], lam[2], lam[3]);
      dst[1] = make_float4(lam[4], lam[5], lam[6], lam[7]);
      etaOut[t * 8 + i] = eta;
    }
    lamw = lamw_n;
    wmu = wmu_n;
  }
}

// 1024 blocks: (b,t) = blockIdx>>2, quarter = blockIdx&3; 500 cells per block.
extern "C" __global__ void __launch_bounds__(256)
k_phase_b(const float* __restrict__ lam0_ws, const float* __restrict__ eta0_ws,
          const float* __restrict__ table, float* __restrict__ out) {
  const int bt = blockIdx.x >> 2;
  const int quarter = blockIdx.x & 3;
  __shared__ float sL[64];
  __shared__ float sE[8];
  if (threadIdx.x < 64) sL[threadIdx.x] = lam0_ws[bt * 64 + threadIdx.x];
  if (threadIdx.x < 8) sE[threadIdx.x] = eta0_ws[bt * 8 + threadIdx.x];
  __syncthreads();
  float A0[D_][D_], e0[D_];
#pragma unroll
  for (int ii = 0; ii < D_; ++ii) {
    e0[ii] = sE[ii];
#pragma unroll
    for (int j = 0; j < D_; ++j) A0[ii][j] = sL[ii * 8 + j];
  }
  float zero[D_];
#pragma unroll
  for (int j = 0; j < D_; ++j) zero[j] = 0.f;
  float ld0;
  float q0 = chol_quad(A0, zero, e0, ld0);
  const float zeta0 = -0.5f * (8.f * LOG2PI_F - ld0 + q0);

#pragma unroll 1
  for (int it = 0; it < 2; ++it) {
    int off = it * 256 + threadIdx.x;
    if (off < 500) {
      int v = quarter * 500 + off;
      float dl[D_], ef[D_];
#pragma unroll
      for (int j = 0; j < D_; ++j) {
        dl[j] = table[j * V_ + v];
        ef[j] = e0[j] + table[(D_ + j) * V_ + v];
      }
      float z1 = table[16 * V_ + v];
      float ldn;
      float qn = chol_quad(A0, dl, ef, ldn);
      float zeta_n = -0.5f * (8.f * LOG2PI_F - ldn + qn);
      out[bt * V_ + v] = zeta0 + z1 - zeta_n;
    }
  }
}

extern "C" void kernel_launch(void* const* d_in, const int* in_sizes, int n_in,
                              void* d_out, int out_size, void* d_ws, size_t ws_size,
                              hipStream_t stream) {
  const int* sent = (const int*)d_in[0];
  const float* em_mu = (const float*)d_in[2];
  const float* em_cho = (const float*)d_in[3];
  const float* tr_mu = (const float*)d_in[4];
  const float* tr_cho = (const float*)d_in[5];
  const float* dec_mu = (const float*)d_in[6];
  const float* dec_cho = (const float*)d_in[7];
  float* out = (float*)d_out;

  float* ws = (float*)d_ws;
  float* lam0_ws = ws;                     // 256*64 floats
  float* eta0_ws = ws + 256 * 64;          // 256*8 floats
  float* table = ws + 256 * 64 + 256 * 8;  // 17*2000 floats

  dim3 g1(B_ + (V_ + 63) / 64);
  k_scan_table<<<g1, dim3(64), 0, stream>>>(sent, em_mu, em_cho, tr_mu, tr_cho,
                                            dec_mu, dec_cho, lam0_ws, eta0_ws, table);
  k_phase_b<<<dim3(1024), dim3(256), 0, stream>>>(lam0_ws, eta0_ws, table, out);
}